// Round 3
// baseline (186.522 us; speedup 1.0000x reference)
//
#include <hip/hip_runtime.h>

// Problem constants (from reference): B=32, I=256, J=2048, C=512, f32 in/out.
#define B_ 32
#define I_ 256
#define J_ 2048
#define C_ 512
#define ROWS_PER_BLOCK 2
#define THREADS (128 * ROWS_PER_BLOCK)

// Masks are monotone prefixes (arange < len), so valid length = lower_bound of
// first zero. 8 iters for I=256, 11 for J=2048 — uniform per block, so the
// loads scalarize and hit L2 after the first blocks touch each row.
__device__ __forceinline__ int mask_len_i32(const int* __restrict__ m, int n) {
    int lo = 0, hi = n;
    while (lo < hi) { int mid = (lo + hi) >> 1; if (m[mid]) lo = mid + 1; else hi = mid; }
    return lo;
}
__device__ __forceinline__ int mask_len_u8(const unsigned char* __restrict__ m, int n) {
    int lo = 0, hi = n;
    while (lo < hi) { int mid = (lo + hi) >> 1; if (m[mid]) lo = mid + 1; else hi = mid; }
    return lo;
}

// One fused kernel: each block owns ROWS_PER_BLOCK output rows of one sample.
// Per row: align_corners=False source position (exact reference op order),
// gather two 2KB rows, lerp with float4 lanes, zero the padded tail (d_out is
// re-poisoned to 0xAA before every timed call, so tail rows must be written).
__global__ __launch_bounds__(THREADS)
void resample_fused(const float* __restrict__ mel,
                    const void* __restrict__ text_mask,
                    const void* __restrict__ mel_mask,
                    float* __restrict__ out) {
    const int rb = blockIdx.x * ROWS_PER_BLOCK + (threadIdx.x >> 7); // global out row
    const int b  = rb >> 8;              // I_ == 256; ROWS_PER_BLOCK | 256 so b is
    const int i  = rb & (I_ - 1);        // uniform per block (rows never straddle b)
    const int c4 = threadIdx.x & 127;    // float4 lane within the row

    // Layout probe: first mel_mask element is guaranteed true (mel_len >= J/2).
    // int32 bool -> word0 == 1 ; packed uint8 bool -> word0 == 0x01010101.
    const unsigned int probe = ((const unsigned int*)mel_mask)[0];
    int L, T;
    if (probe > 1u) {
        L = mask_len_u8((const unsigned char*)text_mask + b * I_, I_);
        T = mask_len_u8((const unsigned char*)mel_mask  + b * J_, J_);
    } else {
        L = mask_len_i32((const int*)text_mask + b * I_, I_);
        T = mask_len_i32((const int*)mel_mask  + b * J_, J_);
    }

    float4* orow = (float4*)(out + (size_t)rb * C_);

    if (i >= L) {                        // padded tail -> zeros
        orow[c4] = make_float4(0.f, 0.f, 0.f, 0.f);
        return;
    }

    const float Tf = (float)T;
    const float Lf = (float)(L > 0 ? L : 1);
    float pos = ((float)i + 0.5f) * Tf / Lf - 0.5f;
    pos = fminf(fmaxf(pos, 0.0f), Tf - 1.0f);
    int i0 = (int)floorf(pos);
    if (i0 < 0) i0 = 0;                  // degenerate-T safety
    int i1 = min(i0 + 1, T - 1);
    if (i1 < 0) i1 = 0;
    const float w  = pos - (float)i0;
    const float iw = 1.0f - w;

    const float4* g0 = (const float4*)(mel + ((size_t)b * J_ + i0) * C_);
    const float4* g1 = (const float4*)(mel + ((size_t)b * J_ + i1) * C_);
    const float4 a = g0[c4];
    const float4 v = g1[c4];

    float4 r;
    r.x = iw * a.x + w * v.x;
    r.y = iw * a.y + w * v.y;
    r.z = iw * a.z + w * v.z;
    r.w = iw * a.w + w * v.w;
    orow[c4] = r;
}

extern "C" void kernel_launch(void* const* d_in, const int* in_sizes, int n_in,
                              void* d_out, int out_size, void* d_ws, size_t ws_size,
                              hipStream_t stream) {
    // Input order per setup_inputs(): 0 mel_embeddings (f32, B*J*C),
    // 1 durations_normalized (unused by reference), 2 text_mask, 3 mel_mask.
    const float* mel       = (const float*)d_in[0];
    const void*  text_mask = d_in[2];
    const void*  mel_mask  = d_in[3];
    float* out = (float*)d_out;

    resample_fused<<<(B_ * I_) / ROWS_PER_BLOCK, THREADS, 0, stream>>>(
        mel, text_mask, mel_mask, out);
}

// Round 4
// 177.712 us; speedup vs baseline: 1.0496x; 1.0496x over previous
//
#include <hip/hip_runtime.h>

// Problem constants (from reference): B=32, I=256, J=2048, C=512, f32 in/out.
#define B_ 32
#define I_ 256
#define J_ 2048
#define C_ 512
#define RPB 4                 // rows per block = waves per block
#define THREADS (64 * RPB)

// Butterfly reduce: every lane ends with the wave-wide sum.
__device__ __forceinline__ int wave_sum_all(int v) {
#pragma unroll
    for (int off = 1; off < 64; off <<= 1) v += __shfl_xor(v, off);
    return v;
}

// One wave per output row. Lengths L,T computed per-wave via lane-parallel
// mask sums (masks are 0/1), packed into one butterfly reduce — ~500-cycle
// critical path vs ~5000 for the former binary search. No LDS, no barriers.
__global__ __launch_bounds__(THREADS)
void resample_fused(const float* __restrict__ mel,
                    const void* __restrict__ text_mask,
                    const void* __restrict__ mel_mask,
                    float* __restrict__ out) {
    const int wid  = threadIdx.x >> 6;
    const int lane = threadIdx.x & 63;
    const int row  = blockIdx.x * RPB + wid;   // global output row (b*I + i)
    const int b    = row >> 8;                 // I_ == 256; RPB | 256 -> rows
    const int i    = row & (I_ - 1);           // never straddle samples

    // Layout probe: first mel_mask element is guaranteed true (mel_len >= J/2).
    // int32 bool -> word0 == 1 ; packed uint8 bool -> word0 == 0x01010101.
    const unsigned int probe = ((const unsigned int*)mel_mask)[0];

    int s_text, s_mel;
    if (probe > 1u) {                          // packed uint8 masks
        const unsigned int* tm = (const unsigned int*)text_mask + b * (I_ / 4);
        const unsigned int* mm = (const unsigned int*)mel_mask  + b * (J_ / 4);
        s_text = __popc(tm[lane] & 0x01010101u);          // 4 bytes/lane
        int s2 = 0;
#pragma unroll
        for (int k = 0; k < J_ / 4 / 64; ++k)             // 8 words/lane
            s2 += __popc(mm[lane + k * 64] & 0x01010101u);
        s_mel = s2;
    } else {                                   // int32 masks
        const int4* tm = (const int4*)((const int*)text_mask + b * I_);
        const int4* mm = (const int4*)((const int*)mel_mask  + b * J_);
        int4 t = tm[lane];                                // 4 words/lane
        s_text = (t.x != 0) + (t.y != 0) + (t.z != 0) + (t.w != 0);
        int s2 = 0;
#pragma unroll
        for (int k = 0; k < J_ / 4 / 64; ++k) {           // 32 words/lane
            int4 m = mm[lane + k * 64];
            s2 += (m.x != 0) + (m.y != 0) + (m.z != 0) + (m.w != 0);
        }
        s_mel = s2;
    }
    // One packed butterfly instead of two: L <= 256 (9 bits), T <= 2048.
    const int packed = wave_sum_all(s_text | (s_mel << 16));
    const int L = packed & 0xFFFF;
    const int T = packed >> 16;

    float4* orow = (float4*)(out + (size_t)row * C_);

    if (i >= L) {                              // padded tail -> zeros (d_out is
        const float4 z = make_float4(0.f, 0.f, 0.f, 0.f);  // poisoned each call)
        orow[lane * 2]     = z;
        orow[lane * 2 + 1] = z;
        return;
    }

    // align_corners=False source position, exact reference op order:
    // pos = (i+0.5)*Tf/Lf - 0.5 ; clip(0, Tf-1) ; i0=floor ; i1=min(i0+1,T-1)
    const float Tf = (float)T;
    const float Lf = (float)(L > 0 ? L : 1);
    float pos = ((float)i + 0.5f) * Tf / Lf - 0.5f;
    pos = fminf(fmaxf(pos, 0.0f), Tf - 1.0f);
    int i0 = (int)floorf(pos);
    if (i0 < 0) i0 = 0;                        // degenerate-T safety
    int i1 = min(i0 + 1, T - 1);
    if (i1 < 0) i1 = 0;
    const float w  = pos - (float)i0;
    const float iw = 1.0f - w;

    const float4* g0 = (const float4*)(mel + ((size_t)b * J_ + i0) * C_);
    const float4* g1 = (const float4*)(mel + ((size_t)b * J_ + i1) * C_);

#pragma unroll
    for (int k = 0; k < 2; ++k) {              // 8 f32 = 32 B per lane
        const float4 a = g0[lane * 2 + k];
        const float4 v = g1[lane * 2 + k];
        float4 r;
        r.x = iw * a.x + w * v.x;
        r.y = iw * a.y + w * v.y;
        r.z = iw * a.z + w * v.z;
        r.w = iw * a.w + w * v.w;
        orow[lane * 2 + k] = r;
    }
}

extern "C" void kernel_launch(void* const* d_in, const int* in_sizes, int n_in,
                              void* d_out, int out_size, void* d_ws, size_t ws_size,
                              hipStream_t stream) {
    // Input order per setup_inputs(): 0 mel_embeddings (f32, B*J*C),
    // 1 durations_normalized (unused by reference), 2 text_mask, 3 mel_mask.
    const float* mel       = (const float*)d_in[0];
    const void*  text_mask = d_in[2];
    const void*  mel_mask  = d_in[3];
    float* out = (float*)d_out;

    resample_fused<<<(B_ * I_) / RPB, THREADS, 0, stream>>>(
        mel, text_mask, mel_mask, out);
}